// Round 10
// baseline (56.980 us; speedup 1.0000x reference)
//
#include <hip/hip_runtime.h>
#include <hip/hip_fp16.h>
#include <math.h>

#define CLIPV 0.03f

struct W9 { float g[9]; };
struct half4 { __half2 a, b; };   // 8 bytes, 2 VGPRs

__device__ __forceinline__ int reflect_idx(int i, int n) {
    if (i < 0) i = -i;
    if (i >= n) i = 2 * n - 2 - i;
    return i;
}

__device__ __forceinline__ float4 h4_to_f4(half4 v) {
    const float2 ab = __half22float2(v.a), cd = __half22float2(v.b);
    float4 r; r.x = ab.x; r.y = ab.y; r.z = cd.x; r.w = cd.y; return r;
}
__device__ __forceinline__ half4 f4_to_h4(float4 v) {
    half4 r; r.a = __floats2half2_rn(v.x, v.y); r.b = __floats2half2_rn(v.z, v.w);
    return r;
}

// ---------------------------------------------------------------------------
// Pass 1: W-conv only (x f32 -> t1 fp16). Marching h => NO march-axis window
// => zero warm-up amplification. Per row: 3 overlapping f4 loads (L1-hot,
// edge lanes use the R5/R7-validated reversed-load table), 36 FMA, half4
// store. One wave = 8 rows of one z-plane; depth-1 prefetch.
// Grid: 2048 blocks x 4 waves = 8192 waves = 32 waves/CU.
// bid&7 = XCD owns z-band [32*xcd, 32*xcd+32).
// ---------------------------------------------------------------------------
__global__ __launch_bounds__(256) void w_pass(const float* __restrict__ x,
                                              __half* __restrict__ t1, W9 wt) {
    const int bid = blockIdx.x;
    const int xcd = bid & 7;
    const int k   = bid >> 3;               // 0..255
    const int z   = xcd * 32 + (k >> 3);    // XCD-local z band
    const int wv  = threadIdx.x >> 6;
    const int h0  = (k & 7) * 32 + wv * 8;  // this wave's 8 rows
    const int L   = threadIdx.x & 63;
    const int w4  = L * 4;
    const bool l0 = (L == 0), l63 = (L == 63);
    const int offL = l0 ? 1 : (w4 - 4);     // lane 0 loads cols 1..4, reversed
    const int offR = l63 ? 251 : (w4 + 4);  // lane 63 loads 251..254, reversed

    const float* plane  = x  + (size_t)z * 65536;
    __half*      oplane = t1 + (size_t)z * 65536;

    float4 cL, cC, cR;
    {
        const float* row = plane + (size_t)h0 * 256;
        cL = *(const float4*)(row + offL);
        cC = *(const float4*)(row + w4);
        cR = *(const float4*)(row + offR);
    }

    #pragma unroll
    for (int i = 0; i < 8; ++i) {
        float4 nL, nC, nR;
        if (i < 7) {
            const float* row = plane + (size_t)(h0 + i + 1) * 256;
            nL = *(const float4*)(row + offL);
            nC = *(const float4*)(row + w4);
            nR = *(const float4*)(row + offR);
        }

        float sv[12];
        sv[0] = l0 ? cL.w : cL.x;   // col -4 -> 4
        sv[1] = l0 ? cL.z : cL.y;   // col -3 -> 3
        sv[2] = l0 ? cL.y : cL.z;   // col -2 -> 2
        sv[3] = l0 ? cL.x : cL.w;   // col -1 -> 1
        sv[4] = cC.x; sv[5] = cC.y; sv[6] = cC.z; sv[7] = cC.w;
        sv[8]  = l63 ? cR.w : cR.x; // col 256 -> 254
        sv[9]  = l63 ? cR.z : cR.y; // col 257 -> 253
        sv[10] = l63 ? cR.y : cR.z; // col 258 -> 252
        sv[11] = l63 ? cR.x : cR.w; // col 259 -> 251

        float4 wc;
        {
            float a0 = 0.f, a1 = 0.f, a2 = 0.f, a3 = 0.f;
            #pragma unroll
            for (int j = 0; j < 9; ++j) {
                a0 = fmaf(wt.g[j], sv[j],     a0);
                a1 = fmaf(wt.g[j], sv[j + 1], a1);
                a2 = fmaf(wt.g[j], sv[j + 2], a2);
                a3 = fmaf(wt.g[j], sv[j + 3], a3);
            }
            wc.x = a0; wc.y = a1; wc.z = a2; wc.w = a3;
        }
        *(half4*)(oplane + (size_t)(h0 + i) * 256 + w4) = f4_to_h4(wc);

        cL = nL; cC = nC; cR = nR;
    }
}

// ---------------------------------------------------------------------------
// Pass 2: H-conv (t1 fp16 -> t2 fp16). Lane-local ring march over h,
// chunk 8 (16 iters / 8 outputs). 9-deep f32 ring (unpack once at load),
// 2-deep load pipeline. Grid: 2048 x 4 waves = 32 waves/CU; same XCD z-band.
// ---------------------------------------------------------------------------
__global__ __launch_bounds__(256) void h2_pass(const __half* __restrict__ t1,
                                               __half* __restrict__ t2, W9 wt) {
    const int bid = blockIdx.x;
    const int xcd = bid & 7;
    const int k   = bid >> 3;               // 0..255
    const int z   = xcd * 32 + (k >> 3);
    const int wv  = threadIdx.x >> 6;
    const int h0  = (k & 7) * 32 + wv * 8;  // this wave's 8 output rows
    const int w4  = (threadIdx.x & 63) * 4;

    const __half* plane  = t1 + (size_t)z * 65536;
    __half*       oplane = t2 + (size_t)z * 65536;

    float4 ring[9];

    half4 cur = *(const half4*)(plane + (size_t)reflect_idx(h0 - 4, 256) * 256 + w4);
    half4 nxt = *(const half4*)(plane + (size_t)reflect_idx(h0 - 3, 256) * 256 + w4);

    #pragma unroll
    for (int i = 0; i < 16; ++i) {
        half4 nn;
        if (i < 14)
            nn = *(const half4*)(plane + (size_t)reflect_idx(h0 - 2 + i, 256) * 256 + w4);

        ring[i % 9] = h4_to_f4(cur);   // row h0-4+i (static index after unroll)

        if (i >= 8) {
            float a0 = 0.f, a1 = 0.f, a2 = 0.f, a3 = 0.f;
            #pragma unroll
            for (int j = 0; j < 9; ++j) {
                const float4 v = ring[(i - 8 + j) % 9];
                a0 = fmaf(wt.g[j], v.x, a0);
                a1 = fmaf(wt.g[j], v.y, a1);
                a2 = fmaf(wt.g[j], v.z, a2);
                a3 = fmaf(wt.g[j], v.w, a3);
            }
            float4 o; o.x = a0; o.y = a1; o.z = a2; o.w = a3;
            *(half4*)(oplane + (size_t)(h0 + i - 8) * 256 + w4) = f4_to_h4(o);
        }

        cur = nxt; nxt = nn;
    }
}

// ---------------------------------------------------------------------------
// Pass 3: D-conv + clip (t2 fp16 + x f32 -> out f32). Thread owns one f4
// column, marches a z-chunk of 8 with a 9-deep f32 ring; clip-source x load
// pipelined 1 iter ahead. Grid: 2048 x 4 waves = 32 waves/CU; chunk->XCD
// matches the writer band (chunks 4*xcd..4*xcd+3).
// ---------------------------------------------------------------------------
__global__ __launch_bounds__(256) void d_clip_pass(const __half* __restrict__ t2,
                                                   const float* __restrict__ x,
                                                   float* __restrict__ out, W9 wt) {
    const int bid   = blockIdx.x;
    const int xcd   = bid & 7;
    const int k     = bid >> 3;                  // 0..255
    const int chunk = xcd * 4 + (k & 3);         // 0..31, XCD-local
    const int tile  = k >> 2;                    // 0..63
    const int z0    = chunk * 8;
    const size_t c4 = (size_t)tile * 256 + threadIdx.x;   // f4-col in plane

    const half4*  t4 = (const half4*)t2;         // plane stride 16384 half4s
    const float4* xp = (const float4*)x;
    float4*       o4 = (float4*)out;

    float4 ring[9];

    half4 cur = t4[(size_t)reflect_idx(z0 - 4, 256) * 16384 + c4];
    half4 nxt = t4[(size_t)reflect_idx(z0 - 3, 256) * 16384 + c4];
    float4 cX, nX;

    #pragma unroll
    for (int i = 0; i < 16; ++i) {
        half4 nn;
        if (i < 14)
            nn = t4[(size_t)reflect_idx(z0 - 2 + i, 256) * 16384 + c4];
        if (i >= 7 && i < 15)
            nX = xp[(size_t)(z0 + i - 7) * 16384 + c4];   // clip src, 1 ahead

        ring[i % 9] = h4_to_f4(cur);   // plane z0-4+i

        if (i >= 8) {
            const int z = z0 + i - 8;
            float a0 = 0.f, a1 = 0.f, a2 = 0.f, a3 = 0.f;
            #pragma unroll
            for (int j = 0; j < 9; ++j) {
                const float4 v = ring[(i - 8 + j) % 9];
                a0 = fmaf(wt.g[j], v.x, a0);
                a1 = fmaf(wt.g[j], v.y, a1);
                a2 = fmaf(wt.g[j], v.z, a2);
                a3 = fmaf(wt.g[j], v.w, a3);
            }
            float4 r;
            r.x = fmaxf(fminf(cX.x, a0 + CLIPV), a0 - CLIPV);
            r.y = fmaxf(fminf(cX.y, a1 + CLIPV), a1 - CLIPV);
            r.z = fmaxf(fminf(cX.z, a2 + CLIPV), a2 - CLIPV);
            r.w = fmaxf(fminf(cX.w, a3 + CLIPV), a3 - CLIPV);
            o4[(size_t)z * 16384 + c4] = r;
        }

        cur = nxt; nxt = nn;
        cX = nX;
    }
}

extern "C" void kernel_launch(void* const* d_in, const int* in_sizes, int n_in,
                              void* d_out, int out_size, void* d_ws, size_t ws_size,
                              hipStream_t stream) {
    const float* x = (const float*)d_in[0];
    float* out = (float*)d_out;
    __half* t1 = (__half*)d_ws;            // 32 MB
    __half* t2 = t1 + 16777216;            // 32 MB

    // normalized 1-D Gaussian weights (separable form of the reference kernel)
    W9 wt;
    {
        double g[9], s = 0.0;
        const double sigma = 9.0 / 4.0;
        for (int i = 0; i < 9; ++i) {
            double tt = (i - 4.0) / sigma;
            g[i] = exp(-0.5 * tt * tt);
            s += g[i];
        }
        for (int i = 0; i < 9; ++i) wt.g[i] = (float)(g[i] / s);
    }

    w_pass<<<dim3(2048), dim3(256), 0, stream>>>(x, t1, wt);
    h2_pass<<<dim3(2048), dim3(256), 0, stream>>>(t1, t2, wt);
    d_clip_pass<<<dim3(2048), dim3(256), 0, stream>>>(t2, x, out, wt);
}